// Round 4
// baseline (100.604 us; speedup 1.0000x reference)
//
#include <hip/hip_runtime.h>
#include <hip/hip_cooperative_groups.h>
#include <math.h>

namespace cg = cooperative_groups;

#define NCLUST 16
#define THREADS 256
#define COOP_BLOCKS 512   // 2 blocks/CU -> co-residency safe at ~100 VGPR
#define TKT_BLOCKS 256    // fallback: fewer blocks -> less atomic-ticket herding

// ---------- shared param init (proven in rounds 1/3) ----------
__device__ __forceinline__ void init_params(const float* __restrict__ means,
                                            const float* __restrict__ chols,
                                            const float* __restrict__ weights,
                                            float par[NCLUST][8], float sS[NCLUST][6],
                                            int tid)
{
    if (tid < NCLUST) {
        const int k = tid;
        // chols layout [K,2,2] row-major; tril -> L00, L10, L11
        const float c00 = chols[4*k + 0];
        const float c10 = chols[4*k + 2];
        const float c11 = chols[4*k + 3];
        const float s11 = c00*c00;
        const float s12 = c00*c10;
        const float s22 = c10*c10 + c11*c11;
        const float det = s11*s22 - s12*s12;
        const float invdet = 1.0f / det;
        const float KC = -0.7213475204444817f;   // -0.5 * log2(e)
        const float A = KC * s22 * invdet;
        const float B = KC * (-2.0f * s12) * invdet;
        const float C = KC * s11 * invdet;
        const float mx = means[2*k + 0];
        const float my = means[2*k + 1];
        const float w  = weights[k];
        const float coef = w / (6.283185307179586f * sqrtf(det));
        const float D = -(2.0f*A*mx + B*my);
        const float E = -(2.0f*C*my + B*mx);
        const float F = A*mx*mx + B*mx*my + C*my*my + log2f(fabsf(coef));
        par[k][0] = A;  par[k][1] = B;  par[k][2] = C;
        par[k][3] = D;  par[k][4] = E;  par[k][5] = F;
        par[k][6] = (coef < 0.0f) ? -1.0f : 1.0f;
        sS[k][0] = s11; sS[k][1] = s12; sS[k][2] = s22;
        sS[k][3] = mx;  sS[k][4] = my;  sS[k][5] = w;
    }
}

// ---------- streaming g^2 partial: returns block sum (valid on tid==0) ----------
__device__ __forceinline__ float stream_gsq(const float4* __restrict__ X4, int nvec,
                                            int gidx, int gstride,
                                            const float par[NCLUST][8], int tid)
{
    float a[NCLUST], b[NCLUST], c[NCLUST], d[NCLUST], e[NCLUST], f[NCLUST], sg[NCLUST];
    #pragma unroll
    for (int k = 0; k < NCLUST; ++k) {
        a[k] = par[k][0]; b[k] = par[k][1]; c[k] = par[k][2];
        d[k] = par[k][3]; e[k] = par[k][4]; f[k] = par[k][5];
        sg[k] = par[k][6];
    }
    float acc = 0.0f;
    for (int i = gidx; i < nvec; i += gstride) {
        const float4 v = X4[i];   // two samples: (v.x,v.y), (v.z,v.w)
        const float xx0 = v.x*v.x, xy0 = v.x*v.y, yy0 = v.y*v.y;
        const float xx1 = v.z*v.z, xy1 = v.z*v.w, yy1 = v.w*v.w;
        float g0 = 0.0f, g1 = 0.0f;
        #pragma unroll
        for (int k = 0; k < NCLUST; ++k) {
            float t0 = fmaf(a[k], xx0,
                       fmaf(b[k], xy0,
                       fmaf(c[k], yy0,
                       fmaf(d[k], v.x,
                       fmaf(e[k], v.y, f[k])))));
            g0 = fmaf(sg[k], exp2f(t0), g0);
            float t1 = fmaf(a[k], xx1,
                       fmaf(b[k], xy1,
                       fmaf(c[k], yy1,
                       fmaf(d[k], v.z,
                       fmaf(e[k], v.w, f[k])))));
            g1 = fmaf(sg[k], exp2f(t1), g1);
        }
        acc = fmaf(g0, g0, acc);
        acc = fmaf(g1, g1, acc);
    }
    #pragma unroll
    for (int off = 32; off > 0; off >>= 1)
        acc += __shfl_down(acc, off, 64);
    __shared__ float wsum[THREADS / 64];
    if ((tid & 63) == 0) wsum[tid >> 6] = acc;
    __syncthreads();
    float s = 0.0f;
    if (tid == 0) {
        #pragma unroll
        for (int w = 0; w < THREADS / 64; ++w) s += wsum[w];
    }
    return s;
}

// ---------- finalize: z normalizer + partial reduction + scalar out ----------
__device__ __forceinline__ void finalize(const float par[NCLUST][8], const float sS[NCLUST][6],
                                         const double* __restrict__ partials, int nblocks,
                                         const float* __restrict__ X, int nsamples,
                                         float* __restrict__ out, int tid)
{
    const int i = tid >> 4, j = tid & 15;   // one cluster pair per thread
    const float t11 = sS[i][0] + sS[j][0];
    const float t12 = sS[i][1] + sS[j][1];
    const float t22 = sS[i][2] + sS[j][2];
    const float det = t11*t22 - t12*t12;
    const float mdx = sS[i][3] - sS[j][3];
    const float mdy = sS[i][4] - sS[j][4];
    const float m2 = (t22*mdx*mdx - 2.0f*t12*mdx*mdy + t11*mdy*mdy) / det;
    const float Zij = expf(-0.5f * m2) / (6.283185307179586f * sqrtf(det));
    double zc = (double)(sS[i][5] * sS[j][5] * Zij);

    double ps = 0.0;
    for (int bi = tid; bi < nblocks; bi += THREADS) ps += partials[bi];

    if (tid == 0 && (nsamples & 1)) {   // odd-sample tail (not hit for N=2M)
        const float x = X[2*(nsamples-1)], y = X[2*(nsamples-1)+1];
        float g = 0.0f;
        #pragma unroll
        for (int k = 0; k < NCLUST; ++k) {
            float t = fmaf(par[k][0], x*x,
                      fmaf(par[k][1], x*y,
                      fmaf(par[k][2], y*y,
                      fmaf(par[k][3], x,
                      fmaf(par[k][4], y, par[k][5])))));
            g = fmaf(par[k][6], exp2f(t), g);
        }
        ps += (double)(g*g);
    }

    __shared__ double red[THREADS], red2[THREADS];
    red[tid] = ps;
    red2[tid] = zc;
    __syncthreads();
    for (int s = 128; s > 0; s >>= 1) {
        if (tid < s) { red[tid] += red[tid + s]; red2[tid] += red2[tid + s]; }
        __syncthreads();
    }
    if (tid == 0)
        out[0] = (float)(-(log(red[0]) - log(red2[0])) / (double)nsamples);
}

// ---------- path A: single cooperative dispatch ----------
__global__ __launch_bounds__(THREADS) void gmm_coop(
    const float* __restrict__ X, const float* __restrict__ means,
    const float* __restrict__ chols, const float* __restrict__ weights,
    double* __restrict__ partials, float* __restrict__ out,
    int nvec, int nsamples)
{
    __shared__ float par[NCLUST][8];
    __shared__ float sS[NCLUST][6];
    const int tid = threadIdx.x;
    init_params(means, chols, weights, par, sS, tid);
    __syncthreads();

    const float bs = stream_gsq((const float4*)X, nvec,
                                blockIdx.x * THREADS + tid, COOP_BLOCKS * THREADS,
                                par, tid);
    if (tid == 0) partials[blockIdx.x] = (double)bs;
    __threadfence();                 // release partials device-wide (proven in r3)
    cg::this_grid().sync();
    if (blockIdx.x != 0) return;
    __threadfence();                 // acquire
    finalize(par, sS, partials, COOP_BLOCKS, X, nsamples, out, tid);
}

// ---------- path B: fallback, last-block ticket (round-3 style, fewer blocks) ----------
__global__ __launch_bounds__(THREADS) void gmm_ticket(
    const float* __restrict__ X, const float* __restrict__ means,
    const float* __restrict__ chols, const float* __restrict__ weights,
    unsigned int* __restrict__ ticket, double* __restrict__ partials,
    float* __restrict__ out, int nvec, int nsamples)
{
    __shared__ float par[NCLUST][8];
    __shared__ float sS[NCLUST][6];
    const int tid = threadIdx.x;
    init_params(means, chols, weights, par, sS, tid);
    __syncthreads();

    const float bs = stream_gsq((const float4*)X, nvec,
                                blockIdx.x * THREADS + tid, TKT_BLOCKS * THREADS,
                                par, tid);
    __shared__ int is_last;
    if (tid == 0) {
        partials[blockIdx.x] = (double)bs;
        __threadfence();
        unsigned int t = atomicAdd(ticket, 1u);
        is_last = (t == (unsigned int)(TKT_BLOCKS - 1)) ? 1 : 0;
    }
    __syncthreads();
    if (!is_last) return;
    __threadfence();
    finalize(par, sS, partials, TKT_BLOCKS, X, nsamples, out, tid);
}

extern "C" void kernel_launch(void* const* d_in, const int* in_sizes, int n_in,
                              void* d_out, int out_size, void* d_ws, size_t ws_size,
                              hipStream_t stream)
{
    const float* X       = (const float*)d_in[0];
    const float* means   = (const float*)d_in[1];
    const float* chols   = (const float*)d_in[2];
    const float* weights = (const float*)d_in[3];
    float* out = (float*)d_out;

    // d_ws layout: [0,4) ticket; [256, 256 + 8*COOP_BLOCKS) partials
    unsigned int* ticket = (unsigned int*)d_ws;
    double* partials = (double*)((char*)d_ws + 256);

    int nsamples = in_sizes[0] / 2;   // X is [N,2]
    int nvec = nsamples / 2;          // float4 = 2 samples

    void* args[] = {
        (void*)&X, (void*)&means, (void*)&chols, (void*)&weights,
        (void*)&partials, (void*)&out, (void*)&nvec, (void*)&nsamples
    };
    hipError_t err = hipLaunchCooperativeKernel((const void*)gmm_coop,
                                                dim3(COOP_BLOCKS), dim3(THREADS),
                                                args, 0, stream);
    if (err != hipSuccess) {
        // deterministic per-machine fallback: memset node + ticket kernel
        hipMemsetAsync(ticket, 0, sizeof(unsigned int), stream);
        gmm_ticket<<<TKT_BLOCKS, THREADS, 0, stream>>>(
            X, means, chols, weights, ticket, partials, out, nvec, nsamples);
    }
}

// Round 5
// 16.259 us; speedup vs baseline: 6.1875x; 6.1875x over previous
//
#include <hip/hip_runtime.h>
#include <math.h>

#define NCLUST 16
#define MAIN_BLOCKS 512
#define THREADS 256

typedef float f32x2 __attribute__((ext_vector_type(2)));

// Pass 1: stream X, packed-fp32 math (v_pk_fma_f32 pairing of the two samples
// in each float4), per-block double partial. No fences, no atomics.
__global__ __launch_bounds__(THREADS) void gmm_main_kernel(
    const float* __restrict__ X,
    const float* __restrict__ means,
    const float* __restrict__ chols,
    const float* __restrict__ weights,
    double* __restrict__ partials,
    int nvec)
{
    __shared__ float par[NCLUST][8];
    const int tid = threadIdx.x;
    if (tid < NCLUST) {
        const int k = tid;
        // chols layout [K,2,2] row-major; tril -> L00, L10, L11
        const float c00 = chols[4*k + 0];
        const float c10 = chols[4*k + 2];
        const float c11 = chols[4*k + 3];
        const float s11 = c00*c00;                 // S = L L^T
        const float s12 = c00*c10;
        const float s22 = c10*c10 + c11*c11;
        const float det = s11*s22 - s12*s12;
        const float invdet = 1.0f / det;
        const float KC = -0.7213475204444817f;     // -0.5 * log2(e)
        const float A = KC * s22 * invdet;
        const float B = KC * (-2.0f * s12) * invdet;
        const float C = KC * s11 * invdet;
        const float mx = means[2*k + 0];
        const float my = means[2*k + 1];
        const float coef = weights[k] / (6.283185307179586f * sqrtf(det));
        // t(x,y) = A x^2 + B xy + C y^2 + D x + E y + F ; exp(-m/2)*|coef| = 2^t
        const float D = -(2.0f*A*mx + B*my);
        const float E = -(2.0f*C*my + B*mx);
        const float F = A*mx*mx + B*mx*my + C*my*my + log2f(fabsf(coef));
        par[k][0] = A;  par[k][1] = B;  par[k][2] = C;
        par[k][3] = D;  par[k][4] = E;  par[k][5] = F;
        par[k][6] = (coef < 0.0f) ? -1.0f : 1.0f;
    }
    __syncthreads();

    float a[NCLUST], b[NCLUST], c[NCLUST], d[NCLUST], e[NCLUST], f[NCLUST], sg[NCLUST];
    #pragma unroll
    for (int k = 0; k < NCLUST; ++k) {
        a[k] = par[k][0]; b[k] = par[k][1]; c[k] = par[k][2];
        d[k] = par[k][3]; e[k] = par[k][4]; f[k] = par[k][5];
        sg[k] = par[k][6];
    }

    const float4* __restrict__ X4 = (const float4*)X;
    f32x2 acc2 = {0.0f, 0.0f};
    const int stride = MAIN_BLOCKS * THREADS;
    for (int i = blockIdx.x * THREADS + tid; i < nvec; i += stride) {
        const float4 v = X4[i];            // two samples: (v.x,v.y), (v.z,v.w)
        const f32x2 px = {v.x, v.z};
        const f32x2 py = {v.y, v.w};
        f32x2 g = {0.0f, 0.0f};
        #pragma unroll
        for (int k = 0; k < NCLUST; ++k) {
            // t = px*(A*px + B*py + D) + (py*(C*py + E) + F)   [5 pk-fma]
            const f32x2 u  = a[k]*px + (b[k]*py + d[k]);
            const f32x2 w2 = c[k]*py + e[k];
            const f32x2 t  = u*px + (w2*py + f[k]);
            const f32x2 ev = { __builtin_amdgcn_exp2f(t.x),
                               __builtin_amdgcn_exp2f(t.y) };
            g = sg[k]*ev + g;              // 1 pk-fma
        }
        acc2 = g*g + acc2;                 // 1 pk-fma
    }
    float acc = acc2.x + acc2.y;

    // wave (64-lane) reduction, then cross-wave via LDS
    #pragma unroll
    for (int off = 32; off > 0; off >>= 1)
        acc += __shfl_down(acc, off, 64);
    __shared__ float wsum[THREADS / 64];
    if ((tid & 63) == 0) wsum[tid >> 6] = acc;
    __syncthreads();
    if (tid == 0) {
        float s = 0.0f;
        #pragma unroll
        for (int w = 0; w < THREADS / 64; ++w) s += wsum[w];
        partials[blockIdx.x] = (double)s;
    }
}

// Pass 2: 16x16 pair normalizer z, reduce block partials, final scalar.
__global__ __launch_bounds__(THREADS) void gmm_final_kernel(
    const float* __restrict__ means,
    const float* __restrict__ chols,
    const float* __restrict__ weights,
    const double* __restrict__ partials,
    float* __restrict__ out,
    int nblocks,
    int nsamples)
{
    const int tid = threadIdx.x;
    __shared__ float s11s[NCLUST], s12s[NCLUST], s22s[NCLUST];
    __shared__ float wv[NCLUST], mxs[NCLUST], mys[NCLUST];
    if (tid < NCLUST) {
        const float c00 = chols[4*tid + 0];
        const float c10 = chols[4*tid + 2];
        const float c11 = chols[4*tid + 3];
        s11s[tid] = c00*c00;
        s12s[tid] = c00*c10;
        s22s[tid] = c10*c10 + c11*c11;
        wv[tid]  = weights[tid];
        mxs[tid] = means[2*tid + 0];
        mys[tid] = means[2*tid + 1];
    }
    __syncthreads();

    // one (i,j) cluster pair per thread (256 = 16*16)
    const int i = tid >> 4, j = tid & 15;
    const float t11 = s11s[i] + s11s[j];
    const float t12 = s12s[i] + s12s[j];
    const float t22 = s22s[i] + s22s[j];
    const float det = t11*t22 - t12*t12;
    const float mdx = mxs[i] - mxs[j];
    const float mdy = mys[i] - mys[j];
    const float m2 = (t22*mdx*mdx - 2.0f*t12*mdx*mdy + t11*mdy*mdy) / det;
    const float Zij = expf(-0.5f * m2) / (6.283185307179586f * sqrtf(det));
    double zc = (double)(wv[i] * wv[j] * Zij);

    // sum the per-block g^2 partials (fixed order)
    double ps = 0.0;
    for (int bi = tid; bi < nblocks; bi += THREADS) ps += partials[bi];

    __shared__ double red[THREADS], red2[THREADS];
    red[tid] = ps;
    red2[tid] = zc;
    __syncthreads();
    for (int s = 128; s > 0; s >>= 1) {
        if (tid < s) { red[tid] += red[tid + s]; red2[tid] += red2[tid + s]; }
        __syncthreads();
    }
    if (tid == 0) {
        const double total = red[0];   // sum_n g(x_n)^2
        const double z = red2[0];      // pair normalizer
        out[0] = (float)(-(log(total) - log(z)) / (double)nsamples);
    }
}

extern "C" void kernel_launch(void* const* d_in, const int* in_sizes, int n_in,
                              void* d_out, int out_size, void* d_ws, size_t ws_size,
                              hipStream_t stream)
{
    const float* X       = (const float*)d_in[0];
    const float* means   = (const float*)d_in[1];
    const float* chols   = (const float*)d_in[2];
    const float* weights = (const float*)d_in[3];
    float* out = (float*)d_out;
    double* partials = (double*)d_ws;   // MAIN_BLOCKS doubles

    const int nsamples = in_sizes[0] / 2;   // X is [N,2]
    const int nvec = nsamples / 2;          // float4 = 2 samples

    gmm_main_kernel<<<MAIN_BLOCKS, THREADS, 0, stream>>>(
        X, means, chols, weights, partials, nvec);
    gmm_final_kernel<<<1, THREADS, 0, stream>>>(
        means, chols, weights, partials, out, MAIN_BLOCKS, nsamples);
}